// Round 12
// baseline (537.862 us; speedup 1.0000x reference)
//
#include <hip/hip_runtime.h>
#include <math.h>

#define NNODES 50000
#define NEDGES 800000
#define NPAD   50048   // 782 * 64
#define NSLICE 8
#define SLICEN (NNODES / NSLICE)   // 6250 (CSR build slicing)

typedef unsigned int uint;
typedef unsigned short u16;
typedef __bf16 bf16x8 __attribute__((ext_vector_type(8)));
typedef float f32x4 __attribute__((ext_vector_type(4)));

__device__ __forceinline__ float lrelu(float x){ return x > 0.f ? x : 0.2f*x; }
__device__ __forceinline__ float elu_f(float x){ return x > 0.f ? x : expm1f(x); }
__device__ __forceinline__ u16 f2bf(float f){
    uint u = __float_as_uint(f);
    return (u16)((u + 0x7fffu + ((u >> 16) & 1u)) >> 16);
}
__device__ __forceinline__ float bf2f(u16 h){ return __uint_as_float(((uint)h) << 16); }
__device__ __forceinline__ float blo(uint u){ return __uint_as_float(u << 16); }
__device__ __forceinline__ float bhi(uint u){ return __uint_as_float(u & 0xffff0000u); }
__device__ __forceinline__ uint packbf(float a, float b){ return (uint)f2bf(a) | ((uint)f2bf(b) << 16); }

// Slice-major feature layout: T[slice][node][16 u32], slice s = cols [s*32, s*32+32).
// u32 index of (s, n, cu): (s*NPAD + n)*16 + cu

// ================= one-shot prep: x cast (slice-major), W transposes, Bf, alp2/arp2, cb =================
#define R0 (NPAD*32)
#define R1 (R0 + 256*128)
#define R2 (R1 + 128*384)
#define R3 (R2 + 256)
#define R4 (R3 + 128)
__global__ void prep_all(const float* __restrict__ x,
                         const float* __restrict__ W0, const float* __restrict__ W1,
                         const float* __restrict__ W2, const float* __restrict__ Wr,
                         const float* __restrict__ al2, const float* __restrict__ ar2,
                         const float* __restrict__ b2,
                         u16* __restrict__ Xb, u16* __restrict__ H1b,
                         u16* __restrict__ B01, u16* __restrict__ Bf,
                         float* __restrict__ alp2, float* __restrict__ arp2,
                         float* __restrict__ cb, int N)
{
    int idx = blockIdx.x * blockDim.x + threadIdx.x;
    if (idx < R0) {                                        // x: one float4 -> ushort4, slice-major
        int n = idx >> 5, g = idx & 31;                    // g: float4 index, cols [4g,4g+4)
        int s = g >> 3, cu2 = (g & 7) * 2;                 // slice, u32 offset
        size_t off16 = (((size_t)s * NPAD + n) * 16 + cu2) * 2;
        ushort4 hv = make_ushort4(0,0,0,0);
        if (n < N) {
            float4 v = ((const float4*)x)[idx];
            hv.x = f2bf(v.x); hv.y = f2bf(v.y); hv.z = f2bf(v.z); hv.w = f2bf(v.w);
        } else {
            *(ushort4*)(H1b + off16) = make_ushort4(0,0,0,0);  // zero H1 pad rows
        }
        *(ushort4*)(Xb + off16) = hv;
    } else if (idx < R1) {                                 // W0/W1 transposed bf16 [gcol][128]
        int j = idx - R0, gcol = j >> 7, k = j & 127;
        float v = (gcol < 128) ? W0[k*128 + gcol] : W1[k*128 + (gcol - 128)];
        B01[j] = f2bf(v);
    } else if (idx < R2) {                                 // Bf [128 cols][384 k]
        int j = idx - R1, c = j / 384, k = j - c*384;
        float v = 0.f;
        if (c < 97) {
            if (k < 128)      v = W2[k*194 + c];
            else if (k < 256) v = W2[(k-128)*194 + 97 + c];
            else              v = Wr[(k-256)*194 + c] + Wr[(k-256)*194 + 97 + c];
        }
        Bf[c*384 + k] = f2bf(v);
    } else if (idx < R3) {                                 // alp2/arp2 [2][128]
        int t = idx - R2, k = t & 127, h = t >> 7;
        float sl = 0.f, sr = 0.f;
        for (int d = 0; d < 97; d++) {
            float w = W2[k*194 + h*97 + d];
            sl += w * al2[h*97 + d];
            sr += w * ar2[h*97 + d];
        }
        alp2[h*128 + k] = sl;
        arp2[h*128 + k] = sr;
    } else if (idx < R4) {                                 // cb
        int c = idx - R3;
        if (c < 97) cb[c] = 0.5f * (b2[c] + b2[97 + c]);
    }
}

// ================= GEMM layers 0/1: slice-major A in, slice-major bf16 out, fused el/er =================
__global__ __launch_bounds__(256, 4)
void gemm_l01(const u16* __restrict__ Ab, const u16* __restrict__ Bh, u16* __restrict__ obf,
              const float* __restrict__ alv, const float* __restrict__ arv,
              float* __restrict__ el, float* __restrict__ er, int N)
{
    __shared__ u16 sB[128 * 136];
    const int bm = blockIdx.x * 64;
    const int tid = threadIdx.x, wid = tid >> 6, lane = tid & 63;
    const int lr = lane & 15, q = lane >> 4, lk8 = q << 3;

    bf16x8 aH[4];
    {
        const int row = bm + wid*16 + lr;
        #pragma unroll
        for (int kt = 0; kt < 4; kt++)      // slice = kt, u32 offset = q*4
            aH[kt] = *(const bf16x8*)(Ab + (((size_t)kt * NPAD + row) * 16 + q*4) * 2);
    }
    {
        const int c = tid >> 1, seg = (tid & 1) * 64;
        const u16* g = Bh + (size_t)c * 128 + seg;
        u16* s = sB + c * 136 + seg;
        #pragma unroll
        for (int j = 0; j < 8; j++)
            *(uint4*)(s + j*8) = *(const uint4*)(g + j*8);
    }
    __syncthreads();

    f32x4 acc[8];
    #pragma unroll
    for (int i = 0; i < 8; i++) acc[i] = (f32x4){0.f,0.f,0.f,0.f};

    #pragma unroll
    for (int kt = 0; kt < 4; kt++)
        #pragma unroll
        for (int fs = 0; fs < 8; fs++) {
            bf16x8 b = *(const bf16x8*)(sB + (fs*16 + lr)*136 + kt*32 + lk8);
            acc[fs] = __builtin_amdgcn_mfma_f32_16x16x32_bf16(aH[kt], b, acc[fs], 0, 0, 0);
        }

    float el0[4] = {0,0,0,0}, el1[4] = {0,0,0,0}, er0[4] = {0,0,0,0}, er1[4] = {0,0,0,0};
    #pragma unroll
    for (int fs = 0; fs < 8; fs++) {
        const int col = fs*16 + lr;
        const int cs = col >> 5, ccu = (col >> 1) & 15, cpar = col & 1;
        const float av = alv[col], gv = arv[col];
        #pragma unroll
        for (int v = 0; v < 4; v++) {
            float f = acc[fs][v];
            int row = bm + wid*16 + q*4 + v;
            if (row < N)
                obf[(((size_t)cs * NPAD + row) * 16 + ccu) * 2 + cpar] = f2bf(f);
            if (fs < 4) { el0[v] += f * av; er0[v] += f * gv; }
            else        { el1[v] += f * av; er1[v] += f * gv; }
        }
    }
    #pragma unroll
    for (int off = 1; off < 16; off <<= 1) {
        #pragma unroll
        for (int v = 0; v < 4; v++) {
            el0[v] += __shfl_xor(el0[v], off);
            el1[v] += __shfl_xor(el1[v], off);
            er0[v] += __shfl_xor(er0[v], off);
            er1[v] += __shfl_xor(er1[v], off);
        }
    }
    if (lr == 0) {
        #pragma unroll
        for (int v = 0; v < 4; v++) {
            int row = bm + wid*16 + q*4 + v;
            if (row < N) {
                *(float2*)(el + 2*(size_t)row) = make_float2(el0[v], el1[v]);
                *(float2*)(er + 2*(size_t)row) = make_float2(er0[v], er1[v]);
            }
        }
    }
}

// ================= final GEMM: out = 0.5*([agg0|agg1|h2] @ Bf) + cb (slice-major A) =================
// TA layout: [slice][node][head][16 u32]; Th2: [slice][node][16 u32]
__global__ __launch_bounds__(256, 3)
void gemm_final(const u16* __restrict__ agg01, const u16* __restrict__ h2b,
                const u16* __restrict__ Bf, const float* __restrict__ cb,
                float* __restrict__ out, int N)
{
    __shared__ u16 sB[64 * 392];
    const int bid = blockIdx.x;
    const int x = (bid >> 4) * 8 + (bid & 7);
    const int ct = (bid >> 3) & 1;
    if (x >= NPAD / 64) return;                 // block-uniform
    const int bm = x * 64;
    const int tid = threadIdx.x, wid = tid >> 6, lane = tid & 63;
    const int lr = lane & 15, q = lane >> 4, lk8 = q << 3;

    bf16x8 aF[12];
    {
        const int row = bm + wid*16 + lr;
        #pragma unroll
        for (int kt = 0; kt < 4; kt++)      // agg head0, slice kt
            aF[kt] = *(const bf16x8*)(agg01 + ((((size_t)kt * NPAD + row) * 2 + 0) * 16 + q*4) * 2);
        #pragma unroll
        for (int kt = 4; kt < 8; kt++)      // agg head1, slice kt-4
            aF[kt] = *(const bf16x8*)(agg01 + ((((size_t)(kt-4) * NPAD + row) * 2 + 1) * 16 + q*4) * 2);
        #pragma unroll
        for (int kt = 8; kt < 12; kt++)     // h2, slice kt-8
            aF[kt] = *(const bf16x8*)(h2b + (((size_t)(kt-8) * NPAD + row) * 16 + q*4) * 2);
    }
    {
        const int c = tid >> 2, seg = (tid & 3) * 96;      // 96 u16 = 12 x uint4
        const u16* g = Bf + (size_t)(ct*64 + c) * 384 + seg;
        u16* s = sB + c * 392 + seg;
        #pragma unroll
        for (int j = 0; j < 12; j++)
            *(uint4*)(s + j*8) = *(const uint4*)(g + j*8);
    }
    __syncthreads();

    f32x4 acc[4];
    #pragma unroll
    for (int i = 0; i < 4; i++) acc[i] = (f32x4){0.f,0.f,0.f,0.f};

    #pragma unroll
    for (int kt = 0; kt < 12; kt++)
        #pragma unroll
        for (int fs = 0; fs < 4; fs++) {
            bf16x8 b = *(const bf16x8*)(sB + (fs*16 + lr)*392 + kt*32 + lk8);
            acc[fs] = __builtin_amdgcn_mfma_f32_16x16x32_bf16(aF[kt], b, acc[fs], 0, 0, 0);
        }

    #pragma unroll
    for (int fs = 0; fs < 4; fs++) {
        const int col = ct*64 + fs*16 + lr;
        if (col >= 97) continue;
        const float cbc = cb[col];
        #pragma unroll
        for (int v = 0; v < 4; v++) {
            int row = bm + wid*16 + q*4 + v;
            if (row < N - 1) out[(size_t)row * 97 + col] = 0.5f * acc[fs][v] + cbc;
        }
    }
}

// ================= CSR build: XCD-sliced histogram + scatter =================
__global__ __launch_bounds__(256)
void hist_sliced(const int* __restrict__ dst, int* __restrict__ counts, int E)
{
    const int slice = blockIdx.x & (NSLICE - 1);
    const int lo = slice * SLICEN, hi = lo + SLICEN;
    const int stride = (gridDim.x >> 3) * blockDim.x;
    for (int i = (blockIdx.x >> 3) * blockDim.x + threadIdx.x; i < E; i += stride) {
        int d = dst[i];
        if (d >= lo && d < hi) atomicAdd(&counts[d], 1);
    }
}

__global__ __launch_bounds__(256)
void scatter_sliced(const int* __restrict__ src, const int* __restrict__ dst,
                    int* __restrict__ cursor, int* __restrict__ ssorted, int E)
{
    const int slice = blockIdx.x & (NSLICE - 1);
    const int lo = slice * SLICEN, hi = lo + SLICEN;
    const int stride = (gridDim.x >> 3) * blockDim.x;
    for (int i = (blockIdx.x >> 3) * blockDim.x + threadIdx.x; i < E; i += stride) {
        int d = dst[i];
        if (d >= lo && d < hi) {
            int p = atomicAdd(&cursor[d], 1);
            ssorted[p] = src[i];
        }
    }
}

// single-pass decoupled-lookback scan; also initializes cursor (= exclusive start)
__global__ __launch_bounds__(1024)
void scan_dl(int* __restrict__ cnt_cur, int* __restrict__ row_start,
             int* __restrict__ flags, int* __restrict__ prefixes, int n)
{
    __shared__ int wsum[16];
    __shared__ int sExc;
    const int tid = threadIdx.x, lane = tid & 63, wv = tid >> 6;
    const int i0 = blockIdx.x * 4096 + tid * 4;
    int c[4], v[4];
    #pragma unroll
    for (int j = 0; j < 4; j++) { int i = i0 + j; c[j] = (i < n) ? cnt_cur[i] : 0; }
    v[0] = c[0]; v[1] = v[0] + c[1]; v[2] = v[1] + c[2]; v[3] = v[2] + c[3];
    int t = v[3];
    #pragma unroll
    for (int off = 1; off < 64; off <<= 1) {
        int u = __shfl_up(t, off);
        if (lane >= off) t += u;
    }
    int texcl = t - v[3];
    if (lane == 63) wsum[wv] = t;
    __syncthreads();
    if (tid == 0) {
        int tot = 0;
        #pragma unroll
        for (int w = 0; w < 16; w++) tot += wsum[w];
        int exc = 0;
        if (blockIdx.x > 0) {
            while (atomicAdd(&flags[blockIdx.x - 1], 0) == 0) __builtin_amdgcn_s_sleep(2);
            exc = atomicAdd(&prefixes[blockIdx.x - 1], 0);
        } else {
            row_start[0] = 0;
        }
        atomicExch(&prefixes[blockIdx.x], exc + tot);
        __threadfence();
        atomicExch(&flags[blockIdx.x], 1);
        sExc = exc;
    }
    __syncthreads();
    int woff = sExc + texcl;
    for (int w = 0; w < 16; w++) if (w < wv) woff += wsum[w];
    #pragma unroll
    for (int j = 0; j < 4; j++) {
        int i = i0 + j;
        if (i < n) {
            int inc = woff + v[j];
            row_start[i + 1] = inc;
            cnt_cur[i] = inc - c[j];                       // cursor init = exclusive start
        }
    }
}

// ================= per-edge weights: w0,w1 (bf16-packed, unscaled) + per-node 1/den =================
__global__ __launch_bounds__(256)
void edge_weights(const float* __restrict__ el, const float* __restrict__ er,
                  const int* __restrict__ row_start, const int* __restrict__ ssorted,
                  uint* __restrict__ wbuf, float2* __restrict__ invd)
{
    const int wv = threadIdx.x >> 6, lane = threadIdx.x & 63;
    const int n = blockIdx.x * 4 + wv;
    const int beg = row_start[n];
    const int deg = row_start[n+1] - beg;
    const float2 ern = *(const float2*)(er + 2*(size_t)n);
    float dp0 = 0.f, dp1 = 0.f;
    for (int cb = 0; cb < deg; cb += 64) {
        const int cnt = min(64, deg - cb);
        if (lane < cnt) {
            int s = ssorted[beg + cb + lane];
            float2 e = *(const float2*)(el + 2*(size_t)s);
            float w0 = __expf(lrelu(e.x + ern.x));   // no max subtraction: |logit| small
            float w1 = __expf(lrelu(e.y + ern.y));
            dp0 += w0; dp1 += w1;
            wbuf[beg + cb + lane] = packbf(w0, w1);
        }
    }
    #pragma unroll
    for (int off = 32; off; off >>= 1) { dp0 += __shfl_xor(dp0, off); dp1 += __shfl_xor(dp1, off); }
    if (lane == 0)
        invd[n] = (deg > 0) ? make_float2(1.f/dp0, 1.f/dp1) : make_float2(0.f, 0.f);
}

// ================= column-sliced aggregation (XCD-resident slice tables) =================
// blockIdx&7 -> XCD; slice = (bid&7)>>1 (each slice served by an XCD pair).
// Wave = 16 col-lanes x 4 edge-groups; one node per wave.
// MODE 0: h1 = elu(agg + bias). MODE 1: h2 = elu(agg + bias + res). MODE 2: both-head agg -> TA.
template<int MODE>
__global__ __launch_bounds__(256)
void sagg(const uint* __restrict__ T, const int* __restrict__ row_start,
          const int* __restrict__ ssorted, const uint* __restrict__ wbuf,
          const float2* __restrict__ invd, const float* __restrict__ bias,
          const uint* __restrict__ Tres, uint* __restrict__ Tout)
{
    const int wv = threadIdx.x >> 6, lane = threadIdx.x & 63;
    const int b7 = blockIdx.x & 7;
    const int slice = b7 >> 1;
    const int n = ((blockIdx.x >> 3) * 2 + (b7 & 1)) * 4 + wv;   // < 50000 exactly
    const int cu = lane & 15, eg = lane >> 4;
    const int beg = row_start[n];
    const int deg = row_start[n+1] - beg;
    const uint* __restrict__ Ts = T + (size_t)slice * NPAD * 16;
    float al = 0.f, ah = 0.f, bl = 0.f, bh = 0.f;

    for (int e0 = 0; e0 < deg; e0 += 4) {
        const int e = e0 + eg;
        const bool valid = (e < deg);
        const int idx = beg + e;
        const int s = valid ? ssorted[idx] : 0;
        const uint wp = valid ? wbuf[idx] : 0u;
        const uint U = Ts[(size_t)(uint)s * 16 + cu];
        const float w0 = blo(wp), w1 = bhi(wp);
        if constexpr (MODE < 2) {
            const float w = (slice < 2) ? w0 : w1;     // slice 0,1 = head0; 2,3 = head1
            al += w * blo(U); ah += w * bhi(U);
        } else {
            const float lo = blo(U), hi = bhi(U);
            al += w0 * lo; ah += w0 * hi;
            bl += w1 * lo; bh += w1 * hi;
        }
    }
    al += __shfl_xor(al, 16); al += __shfl_xor(al, 32);
    ah += __shfl_xor(ah, 16); ah += __shfl_xor(ah, 32);
    if constexpr (MODE == 2) {
        bl += __shfl_xor(bl, 16); bl += __shfl_xor(bl, 32);
        bh += __shfl_xor(bh, 16); bh += __shfl_xor(bh, 32);
    }
    if (lane < 16) {                                   // cu == lane
        const float2 iv = invd[n];
        if constexpr (MODE < 2) {
            const float inv = (slice < 2) ? iv.x : iv.y;
            const int col0 = slice*32 + 2*lane;
            float v0 = al * inv + bias[col0];
            float v1 = ah * inv + bias[col0 + 1];
            if constexpr (MODE == 1) {
                uint r = Tres[((size_t)slice * NPAD + n) * 16 + lane];
                v0 += blo(r); v1 += bhi(r);
            }
            v0 = elu_f(v0); v1 = elu_f(v1);
            Tout[((size_t)slice * NPAD + n) * 16 + lane] = packbf(v0, v1);
        } else {
            const size_t b = ((size_t)slice * NPAD + n) * 32 + lane;
            Tout[b]      = packbf(al * iv.x, ah * iv.x);
            Tout[b + 16] = packbf(bl * iv.y, bh * iv.y);
        }
    }
}

// ================= el2/er2 from slice-major h2 =================
__global__ __launch_bounds__(256)
void elr2_kernel(const uint* __restrict__ Th2, const float* __restrict__ alp2,
                 const float* __restrict__ arp2, float* __restrict__ el2,
                 float* __restrict__ er2, int N)
{
    const int wv = threadIdx.x >> 6, lane = threadIdx.x & 63;
    const int n = blockIdx.x * 4 + wv;
    if (n >= N) return;
    const int s = lane >> 4, cu = lane & 15;
    const uint u = Th2[((size_t)s * NPAD + n) * 16 + cu];
    const int c0 = s*32 + 2*cu;
    const float f0 = blo(u), f1 = bhi(u);
    float e0 = f0*alp2[c0]     + f1*alp2[c0+1];
    float e1 = f0*alp2[128+c0] + f1*alp2[129+c0];
    float r0 = f0*arp2[c0]     + f1*arp2[c0+1];
    float r1 = f0*arp2[128+c0] + f1*arp2[129+c0];
    #pragma unroll
    for (int off = 32; off; off >>= 1) {
        e0 += __shfl_xor(e0, off); e1 += __shfl_xor(e1, off);
        r0 += __shfl_xor(r0, off); r1 += __shfl_xor(r1, off);
    }
    if (lane == 0) {
        *(float2*)(el2 + 2*(size_t)n) = make_float2(e0, e1);
        *(float2*)(er2 + 2*(size_t)n) = make_float2(r0, r1);
    }
}

extern "C" void kernel_launch(void* const* d_in, const int* in_sizes, int n_in,
                              void* d_out, int out_size, void* d_ws, size_t ws_size,
                              hipStream_t stream)
{
    const float* x   = (const float*)d_in[0];
    const int*   esrc= (const int*)  d_in[1];
    const int*   edst= (const int*)  d_in[2];
    const float* W0  = (const float*)d_in[3];
    const float* al0 = (const float*)d_in[4];
    const float* ar0 = (const float*)d_in[5];
    const float* b0  = (const float*)d_in[6];
    const float* W1  = (const float*)d_in[7];
    const float* al1 = (const float*)d_in[8];
    const float* ar1 = (const float*)d_in[9];
    const float* b1  = (const float*)d_in[10];
    const float* W2  = (const float*)d_in[11];
    const float* al2 = (const float*)d_in[12];
    const float* ar2 = (const float*)d_in[13];
    const float* b2  = (const float*)d_in[14];
    const float* rW2 = (const float*)d_in[15];
    float* out = (float*)d_out;

    const int N = NNODES, E = NEDGES;
    const int NB = (N + 4095) / 4096;            // 13 scan tiles
    float* ws = (float*)d_ws;
    size_t o = 0;
    auto alloc_f = [&](size_t count) { float* p = ws + o; o += (count + 3) & ~(size_t)3; return p; };
    float*  el    = alloc_f((size_t)N * 2);
    float*  er    = alloc_f((size_t)N * 2);
    float*  el2   = alloc_f((size_t)N * 2);
    float*  er2   = alloc_f((size_t)N * 2);
    float2* invd  = (float2*)alloc_f((size_t)N * 2);
    uint*   wbuf  = (uint*)alloc_f((size_t)E);             // bf16-packed per-edge weights
    uint*   ftb   = (uint*)alloc_f((size_t)NPAD * 64);     // slice-major ft [4][NPAD][16]
    uint*   Th1   = (uint*)alloc_f((size_t)NPAD * 64);     // slice-major h1
    uint*   Tx    = (uint*)alloc_f((size_t)NPAD * 64);     // slice-major x, then h2
    uint*   TA    = (uint*)alloc_f((size_t)NPAD * 128);    // slice-major agg01 [4][NPAD][2][16]
    u16*    B01   = (u16*)alloc_f(256 * 64);               // W0|W1 transposed bf16
    u16*    Bf    = (u16*)alloc_f(128 * 192);              // final-GEMM B' [128][384]
    float*  alp2  = alloc_f(256);
    float*  arp2  = alloc_f(256);
    float*  cbv   = alloc_f(128);
    int* row_start = (int*)alloc_f(N + 4);
    int* cursor    = (int*)alloc_f(N + 64);                // counts/cursor + flags + prefixes
    int* flags     = cursor + N;
    int* prefixes  = cursor + N + 16;
    int* ssorted   = (int*)alloc_f(E + 8);

    // ---- CSR by dst: memset, sliced hist, single-pass scan (inits cursor), sliced scatter ----
    hipMemsetAsync(cursor, 0, (N + 64) * sizeof(int), stream);
    hist_sliced<<<NSLICE * 256, 256, 0, stream>>>(edst, cursor, E);
    scan_dl<<<NB, 1024, 0, stream>>>(cursor, row_start, flags, prefixes, N);
    scatter_sliced<<<NSLICE * 256, 256, 0, stream>>>(esrc, edst, cursor, ssorted, E);

    // ---- all input prep in one kernel ----
    prep_all<<<(R4 + 255) / 256, 256, 0, stream>>>(x, W0, W1, W2, rW2, al2, ar2, b2,
                                                   (u16*)Tx, (u16*)Th1, B01, Bf, alp2, arp2, cbv, N);

    const int gx = NPAD / 64;                    // 782
    const int node_grid = N / 4;                 // 12500
    const int sagg_grid = (N / 4) * 4;           // 50000: 6250 per XCD-slot x 8

    // ---- layer 0 ----
    gemm_l01<<<gx, 256, 0, stream>>>((u16*)Tx, B01, (u16*)ftb, al0, ar0, el, er, N);
    edge_weights<<<node_grid, 256, 0, stream>>>(el, er, row_start, ssorted, wbuf, invd);
    sagg<0><<<sagg_grid, 256, 0, stream>>>(ftb, row_start, ssorted, wbuf, invd, b0, nullptr, Th1);

    // ---- layer 1 (identity residual from Th1) ----
    gemm_l01<<<gx, 256, 0, stream>>>((u16*)Th1, B01 + 128*128, (u16*)ftb, al1, ar1, el, er, N);
    edge_weights<<<node_grid, 256, 0, stream>>>(el, er, row_start, ssorted, wbuf, invd);
    sagg<1><<<sagg_grid, 256, 0, stream>>>(ftb, row_start, ssorted, wbuf, invd, b1, Th1, Tx);

    // ---- layer 2: el2/er2 from h2, weights, both-head agg, fused output GEMM ----
    elr2_kernel<<<node_grid, 256, 0, stream>>>(Tx, alp2, arp2, el2, er2, N);
    edge_weights<<<node_grid, 256, 0, stream>>>(el2, er2, row_start, ssorted, wbuf, invd);
    sagg<2><<<sagg_grid, 256, 0, stream>>>(Tx, row_start, ssorted, wbuf, invd, b0, nullptr, TA);
    gemm_final<<<((gx + 7) / 8) * 16, 256, 0, stream>>>((u16*)TA, (u16*)Tx, Bf, cbv, out, N);
}

// Round 13
// 275.114 us; speedup vs baseline: 1.9551x; 1.9551x over previous
//
#include <hip/hip_runtime.h>
#include <math.h>

#define NNODES 50000
#define NEDGES 800000
#define NPAD   50048   // 782 * 64
#define NSLICE 8
#define SLICEN (NNODES / NSLICE)   // 6250

typedef unsigned int uint;
typedef unsigned short u16;
typedef __bf16 bf16x8 __attribute__((ext_vector_type(8)));
typedef float f32x4 __attribute__((ext_vector_type(4)));

__device__ __forceinline__ float lrelu(float x){ return x > 0.f ? x : 0.2f*x; }
__device__ __forceinline__ float elu_f(float x){ return x > 0.f ? x : expm1f(x); }
__device__ __forceinline__ u16 f2bf(float f){
    uint u = __float_as_uint(f);
    return (u16)((u + 0x7fffu + ((u >> 16) & 1u)) >> 16);
}
__device__ __forceinline__ float bf2f(u16 h){ return __uint_as_float(((uint)h) << 16); }
__device__ __forceinline__ float blo(uint u){ return __uint_as_float(u << 16); }
__device__ __forceinline__ float bhi(uint u){ return __uint_as_float(u & 0xffff0000u); }

// ================= one-shot prep: x cast, W0/W1 transpose, Bf build, alp2/arp2, cb =================
#define R0 (NPAD*32)
#define R1 (R0 + 256*128)
#define R2 (R1 + 128*384)
#define R3 (R2 + 256)
#define R4 (R3 + 128)
__global__ void prep_all(const float* __restrict__ x,
                         const float* __restrict__ W0, const float* __restrict__ W1,
                         const float* __restrict__ W2, const float* __restrict__ Wr,
                         const float* __restrict__ al2, const float* __restrict__ ar2,
                         const float* __restrict__ b2,
                         u16* __restrict__ Xb, u16* __restrict__ H1b,
                         u16* __restrict__ B01, u16* __restrict__ Bf,
                         float* __restrict__ alp2, float* __restrict__ arp2,
                         float* __restrict__ cb, int N)
{
    int idx = blockIdx.x * blockDim.x + threadIdx.x;
    if (idx < R0) {                                        // x: one float4 -> ushort4
        int n = idx >> 5;
        ushort4 hv = make_ushort4(0,0,0,0);
        if (n < N) {
            float4 v = ((const float4*)x)[idx];
            hv.x = f2bf(v.x); hv.y = f2bf(v.y); hv.z = f2bf(v.z); hv.w = f2bf(v.w);
        } else {
            ((ushort4*)H1b)[idx] = make_ushort4(0,0,0,0);  // zero H1 pad rows
        }
        ((ushort4*)Xb)[idx] = hv;
    } else if (idx < R1) {                                 // W0/W1 transposed bf16 [gcol][128]
        int j = idx - R0, gcol = j >> 7, k = j & 127;
        float v = (gcol < 128) ? W0[k*128 + gcol] : W1[k*128 + (gcol - 128)];
        B01[j] = f2bf(v);
    } else if (idx < R2) {                                 // Bf [128 cols][384 k]
        int j = idx - R1, c = j / 384, k = j - c*384;
        float v = 0.f;
        if (c < 97) {
            if (k < 128)      v = W2[k*194 + c];
            else if (k < 256) v = W2[(k-128)*194 + 97 + c];
            else              v = Wr[(k-256)*194 + c] + Wr[(k-256)*194 + 97 + c];
        }
        Bf[c*384 + k] = f2bf(v);
    } else if (idx < R3) {                                 // alp2/arp2 [2][128]
        int t = idx - R2, k = t & 127, h = t >> 7;
        float sl = 0.f, sr = 0.f;
        for (int d = 0; d < 97; d++) {
            float w = W2[k*194 + h*97 + d];
            sl += w * al2[h*97 + d];
            sr += w * ar2[h*97 + d];
        }
        alp2[h*128 + k] = sl;
        arp2[h*128 + k] = sr;
    } else if (idx < R4) {                                 // cb
        int c = idx - R3;
        if (c < 97) cb[c] = 0.5f * (b2[c] + b2[97 + c]);
    }
}

// ================= GEMM layers 0/1: Cc=128, fused el/er epilogue, bf16 A =================
__global__ __launch_bounds__(256, 4)
void gemm_l01(const u16* __restrict__ Ab, const u16* __restrict__ Bh, u16* __restrict__ obf,
              const float* __restrict__ alv, const float* __restrict__ arv,
              float* __restrict__ el, float* __restrict__ er, int N)
{
    __shared__ u16 sB[128 * 136];
    const int bm = blockIdx.x * 64;
    const int tid = threadIdx.x, wid = tid >> 6, lane = tid & 63;
    const int lr = lane & 15, q = lane >> 4, lk8 = q << 3;

    bf16x8 aH[4];
    {
        size_t abase = (size_t)(bm + wid*16 + lr) * 128 + lk8;
        #pragma unroll
        for (int kt = 0; kt < 4; kt++)
            aH[kt] = *(const bf16x8*)(Ab + abase + kt*32);
    }
    {
        const int c = tid >> 1, seg = (tid & 1) * 64;
        const u16* g = Bh + (size_t)c * 128 + seg;
        u16* s = sB + c * 136 + seg;
        #pragma unroll
        for (int j = 0; j < 8; j++)
            *(uint4*)(s + j*8) = *(const uint4*)(g + j*8);
    }
    __syncthreads();

    f32x4 acc[8];
    #pragma unroll
    for (int i = 0; i < 8; i++) acc[i] = (f32x4){0.f,0.f,0.f,0.f};

    #pragma unroll
    for (int kt = 0; kt < 4; kt++)
        #pragma unroll
        for (int fs = 0; fs < 8; fs++) {
            bf16x8 b = *(const bf16x8*)(sB + (fs*16 + lr)*136 + kt*32 + lk8);
            acc[fs] = __builtin_amdgcn_mfma_f32_16x16x32_bf16(aH[kt], b, acc[fs], 0, 0, 0);
        }

    float el0[4] = {0,0,0,0}, el1[4] = {0,0,0,0}, er0[4] = {0,0,0,0}, er1[4] = {0,0,0,0};
    #pragma unroll
    for (int fs = 0; fs < 8; fs++) {
        const int col = fs*16 + lr;
        const float av = alv[col], gv = arv[col];
        #pragma unroll
        for (int v = 0; v < 4; v++) {
            float f = acc[fs][v];
            int row = bm + wid*16 + q*4 + v;
            if (row < N) obf[(size_t)row * 128 + col] = f2bf(f);
            if (fs < 4) { el0[v] += f * av; er0[v] += f * gv; }
            else        { el1[v] += f * av; er1[v] += f * gv; }
        }
    }
    #pragma unroll
    for (int off = 1; off < 16; off <<= 1) {
        #pragma unroll
        for (int v = 0; v < 4; v++) {
            el0[v] += __shfl_xor(el0[v], off);
            el1[v] += __shfl_xor(el1[v], off);
            er0[v] += __shfl_xor(er0[v], off);
            er1[v] += __shfl_xor(er1[v], off);
        }
    }
    if (lr == 0) {
        #pragma unroll
        for (int v = 0; v < 4; v++) {
            int row = bm + wid*16 + q*4 + v;
            if (row < N) {
                *(float2*)(el + 2*(size_t)row) = make_float2(el0[v], el1[v]);
                *(float2*)(er + 2*(size_t)row) = make_float2(er0[v], er1[v]);
            }
        }
    }
}

// ================= final GEMM: out = 0.5*([agg0|agg1|h2] @ Bf) + cb =================
__global__ __launch_bounds__(256, 3)
void gemm_final(const u16* __restrict__ agg01, const u16* __restrict__ h2b,
                const u16* __restrict__ Bf, const float* __restrict__ cb,
                float* __restrict__ out, int N)
{
    __shared__ u16 sB[64 * 392];
    const int bid = blockIdx.x;
    const int x = (bid >> 4) * 8 + (bid & 7);
    const int ct = (bid >> 3) & 1;
    if (x >= NPAD / 64) return;                 // block-uniform
    const int bm = x * 64;
    const int tid = threadIdx.x, wid = tid >> 6, lane = tid & 63;
    const int lr = lane & 15, q = lane >> 4, lk8 = q << 3;

    bf16x8 aF[12];
    {
        const int row = bm + wid*16 + lr;
        const u16* pa = agg01 + (size_t)row * 256;
        #pragma unroll
        for (int kt = 0; kt < 8; kt++)
            aF[kt] = *(const bf16x8*)(pa + kt*32 + lk8);
        const u16* ph = h2b + (size_t)row * 128;
        #pragma unroll
        for (int kt = 0; kt < 4; kt++)
            aF[8 + kt] = *(const bf16x8*)(ph + kt*32 + lk8);
    }
    {
        const int c = tid >> 2, seg = (tid & 3) * 96;      // 96 u16 = 12 x uint4
        const u16* g = Bf + (size_t)(ct*64 + c) * 384 + seg;
        u16* s = sB + c * 392 + seg;
        #pragma unroll
        for (int j = 0; j < 12; j++)
            *(uint4*)(s + j*8) = *(const uint4*)(g + j*8);
    }
    __syncthreads();

    f32x4 acc[4];
    #pragma unroll
    for (int i = 0; i < 4; i++) acc[i] = (f32x4){0.f,0.f,0.f,0.f};

    #pragma unroll
    for (int kt = 0; kt < 12; kt++)
        #pragma unroll
        for (int fs = 0; fs < 4; fs++) {
            bf16x8 b = *(const bf16x8*)(sB + (fs*16 + lr)*392 + kt*32 + lk8);
            acc[fs] = __builtin_amdgcn_mfma_f32_16x16x32_bf16(aF[kt], b, acc[fs], 0, 0, 0);
        }

    #pragma unroll
    for (int fs = 0; fs < 4; fs++) {
        const int col = ct*64 + fs*16 + lr;
        if (col >= 97) continue;
        const float cbc = cb[col];
        #pragma unroll
        for (int v = 0; v < 4; v++) {
            int row = bm + wid*16 + q*4 + v;
            if (row < N - 1) out[(size_t)row * 97 + col] = 0.5f * acc[fs][v] + cbc;
        }
    }
}

// ================= CSR build: XCD-sliced histogram + scatter (dedicated grids) =================
__global__ __launch_bounds__(256)
void hist_sliced(const int* __restrict__ dst, int* __restrict__ counts, int E)
{
    const int slice = blockIdx.x & (NSLICE - 1);
    const int lo = slice * SLICEN, hi = lo + SLICEN;
    const int stride = (gridDim.x >> 3) * blockDim.x;
    for (int i = (blockIdx.x >> 3) * blockDim.x + threadIdx.x; i < E; i += stride) {
        int d = dst[i];
        if (d >= lo && d < hi) atomicAdd(&counts[d], 1);
    }
}

__global__ __launch_bounds__(256)
void scatter_sliced(const int* __restrict__ src, const int* __restrict__ dst,
                    int* __restrict__ cursor, int* __restrict__ ssorted, int E)
{
    const int slice = blockIdx.x & (NSLICE - 1);
    const int lo = slice * SLICEN, hi = lo + SLICEN;
    const int stride = (gridDim.x >> 3) * blockDim.x;
    for (int i = (blockIdx.x >> 3) * blockDim.x + threadIdx.x; i < E; i += stride) {
        int d = dst[i];
        if (d >= lo && d < hi) {
            int p = atomicAdd(&cursor[d], 1);
            ssorted[p] = src[i];
        }
    }
}

// single-pass decoupled-lookback scan; also initializes cursor (= exclusive start)
__global__ __launch_bounds__(1024)
void scan_dl(int* __restrict__ cnt_cur, int* __restrict__ row_start,
             int* __restrict__ flags, int* __restrict__ prefixes, int n)
{
    __shared__ int wsum[16];
    __shared__ int sExc;
    const int tid = threadIdx.x, lane = tid & 63, wv = tid >> 6;
    const int i0 = blockIdx.x * 4096 + tid * 4;
    int c[4], v[4];
    #pragma unroll
    for (int j = 0; j < 4; j++) { int i = i0 + j; c[j] = (i < n) ? cnt_cur[i] : 0; }
    v[0] = c[0]; v[1] = v[0] + c[1]; v[2] = v[1] + c[2]; v[3] = v[2] + c[3];
    int t = v[3];
    #pragma unroll
    for (int off = 1; off < 64; off <<= 1) {
        int u = __shfl_up(t, off);
        if (lane >= off) t += u;
    }
    int texcl = t - v[3];
    if (lane == 63) wsum[wv] = t;
    __syncthreads();
    if (tid == 0) {
        int tot = 0;
        #pragma unroll
        for (int w = 0; w < 16; w++) tot += wsum[w];
        int exc = 0;
        if (blockIdx.x > 0) {
            while (atomicAdd(&flags[blockIdx.x - 1], 0) == 0) __builtin_amdgcn_s_sleep(2);
            exc = atomicAdd(&prefixes[blockIdx.x - 1], 0);
        } else {
            row_start[0] = 0;
        }
        atomicExch(&prefixes[blockIdx.x], exc + tot);
        __threadfence();
        atomicExch(&flags[blockIdx.x], 1);
        sExc = exc;
    }
    __syncthreads();
    int woff = sExc + texcl;
    for (int w = 0; w < 16; w++) if (w < wv) woff += wsum[w];
    #pragma unroll
    for (int j = 0; j < 4; j++) {
        int i = i0 + j;
        if (i < n) {
            int inc = woff + v[j];
            row_start[i + 1] = inc;
            cnt_cur[i] = inc - c[j];                       // cursor init = exclusive start
        }
    }
}

// ================= aggregation, C=128 layers: one wave per dst node =================
// MODE 0: no res. MODE 1: residual from Rb + fused el2/er2 epilogue.
template<int MODE>
__global__ __launch_bounds__(256)
void gat_agg128(const uint* __restrict__ ftb, const float* __restrict__ el,
                const float* __restrict__ er, const int* __restrict__ row_start,
                const int* __restrict__ ssorted, const u16* __restrict__ Rb,
                const float* __restrict__ bias, u16* __restrict__ Hb,
                const float* __restrict__ alp2, const float* __restrict__ arp2,
                float* __restrict__ el2, float* __restrict__ er2)
{
    __shared__ int   s_src[4][64];
    __shared__ float s_w[4][2][64];
    const int wv = threadIdx.x >> 6, lane = threadIdx.x & 63;
    const int n = blockIdx.x * 4 + wv;
    const int beg = row_start[n];
    const int deg = row_start[n+1] - beg;
    const float2 ern = *(const float2*)(er + 2*(size_t)n);
    const int h = lane >> 5;
    float ax = 0.f, ay = 0.f, dp0 = 0.f, dp1 = 0.f;

    for (int cb = 0; cb < deg; cb += 64) {
        const int cnt = min(64, deg - cb);
        float w0 = 0.f, w1 = 0.f; int s = 0;
        if (lane < cnt) {
            s = ssorted[beg + cb + lane];
            float2 e = *(const float2*)(el + 2*(size_t)s);
            w0 = __expf(lrelu(e.x + ern.x));     // no max subtraction: |logit| small
            w1 = __expf(lrelu(e.y + ern.y));
        }
        dp0 += w0; dp1 += w1;
        s_src[wv][lane] = s; s_w[wv][0][lane] = w0; s_w[wv][1][lane] = w1;
        asm volatile("s_waitcnt lgkmcnt(0)" ::: "memory");   // wave-synchronous LDS publish
        int t = 0;
        for (; t + 8 <= cnt; t += 8) {
            int4   sa = *(const int4*)&s_src[wv][t];
            int4   sb = *(const int4*)&s_src[wv][t+4];
            float4 wa = *(const float4*)&s_w[wv][h][t];
            float4 wb = *(const float4*)&s_w[wv][h][t+4];
            int   sv[8] = {sa.x,sa.y,sa.z,sa.w,sb.x,sb.y,sb.z,sb.w};
            float wj[8] = {wa.x,wa.y,wa.z,wa.w,wb.x,wb.y,wb.z,wb.w};
            uint U[8];
            #pragma unroll
            for (int j = 0; j < 8; j++) U[j] = ftb[((uint)sv[j] << 6) + lane];
            #pragma unroll
            for (int j = 0; j < 8; j++) { ax += wj[j]*blo(U[j]); ay += wj[j]*bhi(U[j]); }
        }
        for (; t + 4 <= cnt; t += 4) {
            int4   s4 = *(const int4*)&s_src[wv][t];
            float4 w4 = *(const float4*)&s_w[wv][h][t];
            uint u0 = ftb[((uint)s4.x << 6) + lane];
            uint u1 = ftb[((uint)s4.y << 6) + lane];
            uint u2 = ftb[((uint)s4.z << 6) + lane];
            uint u3 = ftb[((uint)s4.w << 6) + lane];
            ax += w4.x*blo(u0); ay += w4.x*bhi(u0);
            ax += w4.y*blo(u1); ay += w4.y*bhi(u1);
            ax += w4.z*blo(u2); ay += w4.z*bhi(u2);
            ax += w4.w*blo(u3); ay += w4.w*bhi(u3);
        }
        for (; t < cnt; t++) {
            int sv = s_src[wv][t];
            float w = s_w[wv][h][t];
            uint u = ftb[((uint)sv << 6) + lane];
            ax += w*blo(u); ay += w*bhi(u);
        }
    }
    #pragma unroll
    for (int off = 32; off; off >>= 1) { dp0 += __shfl_xor(dp0, off); dp1 += __shfl_xor(dp1, off); }
    const float den = (h == 0) ? dp0 : dp1;
    float r0 = (deg > 0) ? ax / den : 0.f;
    float r1 = (deg > 0) ? ay / den : 0.f;
    const int c0 = 2 * lane;
    const size_t ob = (size_t)n*128 + c0;
    const float2 bv = *(const float2*)(bias + c0);
    float v0 = r0 + bv.x, v1 = r1 + bv.y;
    if (MODE == 1) {
        ushort2 rv = *(const ushort2*)&Rb[ob];
        v0 += bf2f(rv.x);
        v1 += bf2f(rv.y);
    }
    v0 = elu_f(v0); v1 = elu_f(v1);
    *(ushort2*)&Hb[ob] = make_ushort2(f2bf(v0), f2bf(v1));

    if constexpr (MODE == 1) {
        float2 a0 = *(const float2*)(alp2 + c0);
        float2 a1 = *(const float2*)(alp2 + 128 + c0);
        float2 g0 = *(const float2*)(arp2 + c0);
        float2 g1 = *(const float2*)(arp2 + 128 + c0);
        float e0 = v0*a0.x + v1*a0.y;
        float e1 = v0*a1.x + v1*a1.y;
        float f0 = v0*g0.x + v1*g0.y;
        float f1 = v0*g1.x + v1*g1.y;
        #pragma unroll
        for (int off = 32; off; off >>= 1) {
            e0 += __shfl_xor(e0, off); e1 += __shfl_xor(e1, off);
            f0 += __shfl_xor(f0, off); f1 += __shfl_xor(f1, off);
        }
        if (lane == 0) {
            *(float2*)(el2 + 2*(size_t)n) = make_float2(e0, e1);
            *(float2*)(er2 + 2*(size_t)n) = make_float2(f0, f1);
        }
    }
}

// ================= layer-2 aggregation on h2 (linearity trick) =================
__global__ __launch_bounds__(256)
void gat_agg_out2(const uint* __restrict__ h2u, const float* __restrict__ el,
                  const float* __restrict__ er, const int* __restrict__ row_start,
                  const int* __restrict__ ssorted, u16* __restrict__ agg01)
{
    __shared__ int   s_src[4][64];
    __shared__ float s_w[4][2][64];
    const int wv = threadIdx.x >> 6, lane = threadIdx.x & 63;
    const int n = blockIdx.x * 4 + wv;
    const int beg = row_start[n];
    const int deg = row_start[n+1] - beg;
    const float2 ern = *(const float2*)(er + 2*(size_t)n);
    float ax0 = 0.f, ay0 = 0.f, ax1 = 0.f, ay1 = 0.f, dp0 = 0.f, dp1 = 0.f;

    for (int cb = 0; cb < deg; cb += 64) {
        const int cnt = min(64, deg - cb);
        float w0 = 0.f, w1 = 0.f; int s = 0;
        if (lane < cnt) {
            s = ssorted[beg + cb + lane];
            float2 e = *(const float2*)(el + 2*(size_t)s);
            w0 = __expf(lrelu(e.x + ern.x));
            w1 = __expf(lrelu(e.y + ern.y));
        }
        dp0 += w0; dp1 += w1;
        s_src[wv][lane] = s; s_w[wv][0][lane] = w0; s_w[wv][1][lane] = w1;
        asm volatile("s_waitcnt lgkmcnt(0)" ::: "memory");
        int t = 0;
        for (; t + 8 <= cnt; t += 8) {
            int4   sa = *(const int4*)&s_src[wv][t];
            int4   sb = *(const int4*)&s_src[wv][t+4];
            float4 p0a = *(const float4*)&s_w[wv][0][t];
            float4 p0b = *(const float4*)&s_w[wv][0][t+4];
            float4 p1a = *(const float4*)&s_w[wv][1][t];
            float4 p1b = *(const float4*)&s_w[wv][1][t+4];
            int   sv[8] = {sa.x,sa.y,sa.z,sa.w,sb.x,sb.y,sb.z,sb.w};
            float f0[8] = {p0a.x,p0a.y,p0a.z,p0a.w,p0b.x,p0b.y,p0b.z,p0b.w};
            float f1[8] = {p1a.x,p1a.y,p1a.z,p1a.w,p1b.x,p1b.y,p1b.z,p1b.w};
            uint U[8];
            #pragma unroll
            for (int j = 0; j < 8; j++) U[j] = h2u[((uint)sv[j] << 6) + lane];
            #pragma unroll
            for (int j = 0; j < 8; j++) {
                float lo = blo(U[j]), hi = bhi(U[j]);
                ax0 += f0[j]*lo; ay0 += f0[j]*hi;
                ax1 += f1[j]*lo; ay1 += f1[j]*hi;
            }
        }
        for (; t < cnt; t++) {
            int sv = s_src[wv][t];
            float f0 = s_w[wv][0][t], f1 = s_w[wv][1][t];
            uint u = h2u[((uint)sv << 6) + lane];
            float lo = blo(u), hi = bhi(u);
            ax0 += f0*lo; ay0 += f0*hi;
            ax1 += f1*lo; ay1 += f1*hi;
        }
    }
    #pragma unroll
    for (int off = 32; off; off >>= 1) { dp0 += __shfl_xor(dp0, off); dp1 += __shfl_xor(dp1, off); }
    const float i0 = (deg > 0) ? 1.f/dp0 : 0.f;
    const float i1 = (deg > 0) ? 1.f/dp1 : 0.f;
    const int c0 = 2 * lane;
    *(ushort2*)&agg01[(size_t)n*256 + c0]       = make_ushort2(f2bf(ax0*i0), f2bf(ay0*i0));
    *(ushort2*)&agg01[(size_t)n*256 + 128 + c0] = make_ushort2(f2bf(ax1*i1), f2bf(ay1*i1));
}

extern "C" void kernel_launch(void* const* d_in, const int* in_sizes, int n_in,
                              void* d_out, int out_size, void* d_ws, size_t ws_size,
                              hipStream_t stream)
{
    const float* x   = (const float*)d_in[0];
    const int*   esrc= (const int*)  d_in[1];
    const int*   edst= (const int*)  d_in[2];
    const float* W0  = (const float*)d_in[3];
    const float* al0 = (const float*)d_in[4];
    const float* ar0 = (const float*)d_in[5];
    const float* b0  = (const float*)d_in[6];
    const float* W1  = (const float*)d_in[7];
    const float* al1 = (const float*)d_in[8];
    const float* ar1 = (const float*)d_in[9];
    const float* b1  = (const float*)d_in[10];
    const float* W2  = (const float*)d_in[11];
    const float* al2 = (const float*)d_in[12];
    const float* ar2 = (const float*)d_in[13];
    const float* b2  = (const float*)d_in[14];
    const float* rW2 = (const float*)d_in[15];
    float* out = (float*)d_out;

    const int N = NNODES, E = NEDGES;
    const int NB = (N + 4095) / 4096;            // 13 scan tiles
    float* ws = (float*)d_ws;
    size_t o = 0;
    auto alloc_f = [&](size_t count) { float* p = ws + o; o += (count + 3) & ~(size_t)3; return p; };
    float* el    = alloc_f((size_t)N * 2);
    float* er    = alloc_f((size_t)N * 2);
    float* el2   = alloc_f((size_t)N * 2);
    float* er2   = alloc_f((size_t)N * 2);
    uint*  ftb   = (uint*)alloc_f((size_t)N * 64);         // bf16 ft [N][128]
    u16*   agg01 = (u16*)alloc_f((size_t)NPAD * 128);      // bf16 [NPAD][256]
    u16*   Xb    = (u16*)alloc_f((size_t)NPAD * 64);       // bf16 [NPAD][128] (x, then h2)
    u16*   H1b   = (u16*)alloc_f((size_t)NPAD * 64);
    u16*   B01   = (u16*)alloc_f(256 * 64);                // W0|W1 transposed bf16
    u16*   Bf    = (u16*)alloc_f(128 * 192);               // final-GEMM B' [128][384]
    float* alp2  = alloc_f(256);
    float* arp2  = alloc_f(256);
    float* cbv   = alloc_f(128);
    int* row_start = (int*)alloc_f(N + 4);
    int* cursor    = (int*)alloc_f(N + 64);                // counts/cursor + flags + prefixes
    int* flags     = cursor + N;
    int* prefixes  = cursor + N + 16;
    int* ssorted   = (int*)alloc_f(E);

    // ---- CSR by dst: memset, sliced hist, single-pass scan (inits cursor), sliced scatter ----
    hipMemsetAsync(cursor, 0, (N + 64) * sizeof(int), stream);
    hist_sliced<<<NSLICE * 256, 256, 0, stream>>>(edst, cursor, E);
    scan_dl<<<NB, 1024, 0, stream>>>(cursor, row_start, flags, prefixes, N);
    scatter_sliced<<<NSLICE * 256, 256, 0, stream>>>(esrc, edst, cursor, ssorted, E);

    // ---- all input prep in one kernel ----
    prep_all<<<(R4 + 255) / 256, 256, 0, stream>>>(x, W0, W1, W2, rW2, al2, ar2, b2,
                                                   Xb, H1b, B01, Bf, alp2, arp2, cbv, N);

    const int gx = NPAD / 64;                    // 782
    const int agg_grid = N / 4;                  // 12500

    // ---- layer 0 (GEMM + fused el/er) ----
    gemm_l01<<<gx, 256, 0, stream>>>(Xb, B01, (u16*)ftb, al0, ar0, el, er, N);
    gat_agg128<0><<<agg_grid, 256, 0, stream>>>(ftb, el, er, row_start, ssorted,
                                                nullptr, b0, H1b, nullptr, nullptr, nullptr, nullptr);

    // ---- layer 1 (identity residual; epilogue computes h2 + el2/er2) ----
    gemm_l01<<<gx, 256, 0, stream>>>(H1b, B01 + 128*128, (u16*)ftb, al1, ar1, el, er, N);
    gat_agg128<1><<<agg_grid, 256, 0, stream>>>(ftb, el, er, row_start, ssorted,
                                                H1b, b1, Xb, alp2, arp2, el2, er2);

    // ---- layer 2: aggregate h2 per head, then fused output GEMM ----
    gat_agg_out2<<<agg_grid, 256, 0, stream>>>((uint*)Xb, el2, er2, row_start, ssorted, agg01);
    gemm_final<<<((gx + 7) / 8) * 16, 256, 0, stream>>>(agg01, Xb, Bf, cbv, out, N);
}

// Round 15
// 269.309 us; speedup vs baseline: 1.9972x; 1.0216x over previous
//
#include <hip/hip_runtime.h>
#include <math.h>

#define NNODES 50000
#define NEDGES 800000
#define NPAD   50048   // 782 * 64 = 391 * 128
#define NSLICE 8
#define SLICEN (NNODES / NSLICE)   // 6250

typedef unsigned int uint;
typedef unsigned short u16;
typedef __bf16 bf16x8 __attribute__((ext_vector_type(8)));
typedef float f32x4 __attribute__((ext_vector_type(4)));

__device__ __forceinline__ float lrelu(float x){ return x > 0.f ? x : 0.2f*x; }
__device__ __forceinline__ float elu_f(float x){ return x > 0.f ? x : expm1f(x); }
__device__ __forceinline__ u16 f2bf(float f){
    uint u = __float_as_uint(f);
    return (u16)((u + 0x7fffu + ((u >> 16) & 1u)) >> 16);
}
__device__ __forceinline__ float bf2f(u16 h){ return __uint_as_float(((uint)h) << 16); }
__device__ __forceinline__ float blo(uint u){ return __uint_as_float(u << 16); }
__device__ __forceinline__ float bhi(uint u){ return __uint_as_float(u & 0xffff0000u); }

// ================= fused: XCD-sliced histogram (blocks 0..HISTB-1) + one-shot prep =================
// Hist blocks FIRST so blockIdx&7 -> XCD slice affinity matches the standalone kernel.
#define HISTB 2048
#define R0 (NPAD*32)
#define R1 (R0 + 256*128)
#define R2 (R1 + 128*384)
#define R3 (R2 + 256)
#define R4 (R3 + 128)
#define PREPB ((R4 + 255) / 256)
__global__ __launch_bounds__(256)
void prep_hist(const float* __restrict__ x,
               const float* __restrict__ W0, const float* __restrict__ W1,
               const float* __restrict__ W2, const float* __restrict__ Wr,
               const float* __restrict__ al2, const float* __restrict__ ar2,
               const float* __restrict__ b2,
               const int* __restrict__ edst, int* __restrict__ counts,
               u16* __restrict__ Xb, u16* __restrict__ H1b,
               u16* __restrict__ B01, u16* __restrict__ Bf,
               float* __restrict__ alp2, float* __restrict__ arp2,
               float* __restrict__ cb, int N)
{
    if (blockIdx.x < HISTB) {                              // sliced histogram, affinity-preserving
        const int hb = blockIdx.x;
        const int slice = hb & (NSLICE - 1);
        const int lo = slice * SLICEN, hi = lo + SLICEN;
        const int stride = (HISTB >> 3) * 256;
        for (int i = (hb >> 3) * 256 + (int)threadIdx.x; i < NEDGES; i += stride) {
            int d = edst[i];
            if (d >= lo && d < hi) atomicAdd(&counts[d], 1);
        }
        return;
    }
    int idx = (blockIdx.x - HISTB) * 256 + threadIdx.x;
    if (idx < R0) {                                        // x: one float4 -> ushort4
        int n = idx >> 5;
        ushort4 hv = make_ushort4(0,0,0,0);
        if (n < N) {
            float4 v = ((const float4*)x)[idx];
            hv.x = f2bf(v.x); hv.y = f2bf(v.y); hv.z = f2bf(v.z); hv.w = f2bf(v.w);
        } else {
            ((ushort4*)H1b)[idx] = make_ushort4(0,0,0,0);  // zero H1 pad rows
        }
        ((ushort4*)Xb)[idx] = hv;
    } else if (idx < R1) {                                 // W0/W1 transposed bf16 [gcol][128]
        int j = idx - R0, gcol = j >> 7, k = j & 127;
        float v = (gcol < 128) ? W0[k*128 + gcol] : W1[k*128 + (gcol - 128)];
        B01[j] = f2bf(v);
    } else if (idx < R2) {                                 // Bf [128 cols][384 k]
        int j = idx - R1, c = j / 384, k = j - c*384;
        float v = 0.f;
        if (c < 97) {
            if (k < 128)      v = W2[k*194 + c];
            else if (k < 256) v = W2[(k-128)*194 + 97 + c];
            else              v = Wr[(k-256)*194 + c] + Wr[(k-256)*194 + 97 + c];
        }
        Bf[c*384 + k] = f2bf(v);
    } else if (idx < R3) {                                 // alp2/arp2 [2][128]
        int t = idx - R2, k = t & 127, h = t >> 7;
        float sl = 0.f, sr = 0.f;
        for (int d = 0; d < 97; d++) {
            float w = W2[k*194 + h*97 + d];
            sl += w * al2[h*97 + d];
            sr += w * ar2[h*97 + d];
        }
        alp2[h*128 + k] = sl;
        arp2[h*128 + k] = sr;
    } else if (idx < R4) {                                 // cb
        int c = idx - R3;
        if (c < 97) cb[c] = 0.5f * (b2[c] + b2[97 + c]);
    }
}

// ================= GEMM layers 0/1: BM=128 (8 waves), Cc=128, fused el/er epilogue =================
__global__ __launch_bounds__(512, 8)
void gemm_l01(const u16* __restrict__ Ab, const u16* __restrict__ Bh, u16* __restrict__ obf,
              const float* __restrict__ alv, const float* __restrict__ arv,
              float* __restrict__ el, float* __restrict__ er, int N)
{
    __shared__ u16 sB[128 * 136];
    const int bm = blockIdx.x * 128;
    const int tid = threadIdx.x, wid = tid >> 6, lane = tid & 63;
    const int lr = lane & 15, q = lane >> 4, lk8 = q << 3;

    bf16x8 aH[4];
    {
        size_t abase = (size_t)(bm + wid*16 + lr) * 128 + lk8;
        #pragma unroll
        for (int kt = 0; kt < 4; kt++)
            aH[kt] = *(const bf16x8*)(Ab + abase + kt*32);
    }
    {   // stage B: 128 cols x 128 k; 512 threads x 32 u16 = 4 x uint4 each
        const int c = tid >> 2, seg = (tid & 3) * 32;
        const u16* g = Bh + (size_t)c * 128 + seg;
        u16* s = sB + c * 136 + seg;
        #pragma unroll
        for (int j = 0; j < 4; j++)
            *(uint4*)(s + j*8) = *(const uint4*)(g + j*8);
    }
    __syncthreads();

    f32x4 acc[8];
    #pragma unroll
    for (int i = 0; i < 8; i++) acc[i] = (f32x4){0.f,0.f,0.f,0.f};

    #pragma unroll
    for (int kt = 0; kt < 4; kt++)
        #pragma unroll
        for (int fs = 0; fs < 8; fs++) {
            bf16x8 b = *(const bf16x8*)(sB + (fs*16 + lr)*136 + kt*32 + lk8);
            acc[fs] = __builtin_amdgcn_mfma_f32_16x16x32_bf16(aH[kt], b, acc[fs], 0, 0, 0);
        }

    float el0[4] = {0,0,0,0}, el1[4] = {0,0,0,0}, er0[4] = {0,0,0,0}, er1[4] = {0,0,0,0};
    #pragma unroll
    for (int fs = 0; fs < 8; fs++) {
        const int col = fs*16 + lr;
        const float av = alv[col], gv = arv[col];
        #pragma unroll
        for (int v = 0; v < 4; v++) {
            float f = acc[fs][v];
            int row = bm + wid*16 + q*4 + v;
            if (row < N) obf[(size_t)row * 128 + col] = f2bf(f);
            if (fs < 4) { el0[v] += f * av; er0[v] += f * gv; }
            else        { el1[v] += f * av; er1[v] += f * gv; }
        }
    }
    #pragma unroll
    for (int off = 1; off < 16; off <<= 1) {
        #pragma unroll
        for (int v = 0; v < 4; v++) {
            el0[v] += __shfl_xor(el0[v], off);
            el1[v] += __shfl_xor(el1[v], off);
            er0[v] += __shfl_xor(er0[v], off);
            er1[v] += __shfl_xor(er1[v], off);
        }
    }
    if (lr == 0) {
        #pragma unroll
        for (int v = 0; v < 4; v++) {
            int row = bm + wid*16 + q*4 + v;
            if (row < N) {
                *(float2*)(el + 2*(size_t)row) = make_float2(el0[v], el1[v]);
                *(float2*)(er + 2*(size_t)row) = make_float2(er0[v], er1[v]);
            }
        }
    }
}

// ================= final GEMM: out = 0.5*([agg0|agg1|h2] @ Bf) + cb =================
__global__ __launch_bounds__(256, 3)
void gemm_final(const u16* __restrict__ agg01, const u16* __restrict__ h2b,
                const u16* __restrict__ Bf, const float* __restrict__ cb,
                float* __restrict__ out, int N)
{
    __shared__ u16 sB[64 * 392];
    const int bid = blockIdx.x;
    const int x = (bid >> 4) * 8 + (bid & 7);
    const int ct = (bid >> 3) & 1;
    if (x >= NPAD / 64) return;                 // block-uniform
    const int bm = x * 64;
    const int tid = threadIdx.x, wid = tid >> 6, lane = tid & 63;
    const int lr = lane & 15, q = lane >> 4, lk8 = q << 3;

    bf16x8 aF[12];
    {
        const int row = bm + wid*16 + lr;
        const u16* pa = agg01 + (size_t)row * 256;
        #pragma unroll
        for (int kt = 0; kt < 8; kt++)
            aF[kt] = *(const bf16x8*)(pa + kt*32 + lk8);
        const u16* ph = h2b + (size_t)row * 128;
        #pragma unroll
        for (int kt = 0; kt < 4; kt++)
            aF[8 + kt] = *(const bf16x8*)(ph + kt*32 + lk8);
    }
    {
        const int c = tid >> 2, seg = (tid & 3) * 96;      // 96 u16 = 12 x uint4
        const u16* g = Bf + (size_t)(ct*64 + c) * 384 + seg;
        u16* s = sB + c * 392 + seg;
        #pragma unroll
        for (int j = 0; j < 12; j++)
            *(uint4*)(s + j*8) = *(const uint4*)(g + j*8);
    }
    __syncthreads();

    f32x4 acc[4];
    #pragma unroll
    for (int i = 0; i < 4; i++) acc[i] = (f32x4){0.f,0.f,0.f,0.f};

    #pragma unroll
    for (int kt = 0; kt < 12; kt++)
        #pragma unroll
        for (int fs = 0; fs < 4; fs++) {
            bf16x8 b = *(const bf16x8*)(sB + (fs*16 + lr)*392 + kt*32 + lk8);
            acc[fs] = __builtin_amdgcn_mfma_f32_16x16x32_bf16(aF[kt], b, acc[fs], 0, 0, 0);
        }

    #pragma unroll
    for (int fs = 0; fs < 4; fs++) {
        const int col = ct*64 + fs*16 + lr;
        if (col >= 97) continue;
        const float cbc = cb[col];
        #pragma unroll
        for (int v = 0; v < 4; v++) {
            int row = bm + wid*16 + q*4 + v;
            if (row < N - 1) out[(size_t)row * 97 + col] = 0.5f * acc[fs][v] + cbc;
        }
    }
}

// ================= CSR build: sliced scatter (dedicated grid, affinity-preserving) =================
__global__ __launch_bounds__(256)
void scatter_sliced(const int* __restrict__ src, const int* __restrict__ dst,
                    int* __restrict__ cursor, int* __restrict__ ssorted, int E)
{
    const int slice = blockIdx.x & (NSLICE - 1);
    const int lo = slice * SLICEN, hi = lo + SLICEN;
    const int stride = (gridDim.x >> 3) * blockDim.x;
    for (int i = (blockIdx.x >> 3) * blockDim.x + threadIdx.x; i < E; i += stride) {
        int d = dst[i];
        if (d >= lo && d < hi) {
            int p = atomicAdd(&cursor[d], 1);
            ssorted[p] = src[i];
        }
    }
}

// single-pass decoupled-lookback scan; also initializes cursor (= exclusive start)
__global__ __launch_bounds__(1024)
void scan_dl(int* __restrict__ cnt_cur, int* __restrict__ row_start,
             int* __restrict__ flags, int* __restrict__ prefixes, int n)
{
    __shared__ int wsum[16];
    __shared__ int sExc;
    const int tid = threadIdx.x, lane = tid & 63, wv = tid >> 6;
    const int i0 = blockIdx.x * 4096 + tid * 4;
    int c[4], v[4];
    #pragma unroll
    for (int j = 0; j < 4; j++) { int i = i0 + j; c[j] = (i < n) ? cnt_cur[i] : 0; }
    v[0] = c[0]; v[1] = v[0] + c[1]; v[2] = v[1] + c[2]; v[3] = v[2] + c[3];
    int t = v[3];
    #pragma unroll
    for (int off = 1; off < 64; off <<= 1) {
        int u = __shfl_up(t, off);
        if (lane >= off) t += u;
    }
    int texcl = t - v[3];
    if (lane == 63) wsum[wv] = t;
    __syncthreads();
    if (tid == 0) {
        int tot = 0;
        #pragma unroll
        for (int w = 0; w < 16; w++) tot += wsum[w];
        int exc = 0;
        if (blockIdx.x > 0) {
            while (atomicAdd(&flags[blockIdx.x - 1], 0) == 0) __builtin_amdgcn_s_sleep(2);
            exc = atomicAdd(&prefixes[blockIdx.x - 1], 0);
        } else {
            row_start[0] = 0;
        }
        atomicExch(&prefixes[blockIdx.x], exc + tot);
        __threadfence();
        atomicExch(&flags[blockIdx.x], 1);
        sExc = exc;
    }
    __syncthreads();
    int woff = sExc + texcl;
    for (int w = 0; w < 16; w++) if (w < wv) woff += wsum[w];
    #pragma unroll
    for (int j = 0; j < 4; j++) {
        int i = i0 + j;
        if (i < n) {
            int inc = woff + v[j];
            row_start[i + 1] = inc;
            cnt_cur[i] = inc - c[j];                       // cursor init = exclusive start
        }
    }
}

// ================= aggregation, C=128 layers: one wave per dst node =================
// MODE 0: no res. MODE 1: residual from Rb + fused el2/er2 epilogue.
template<int MODE>
__global__ __launch_bounds__(256)
void gat_agg128(const uint* __restrict__ ftb, const float* __restrict__ el,
                const float* __restrict__ er, const int* __restrict__ row_start,
                const int* __restrict__ ssorted, const u16* __restrict__ Rb,
                const float* __restrict__ bias, u16* __restrict__ Hb,
                const float* __restrict__ alp2, const float* __restrict__ arp2,
                float* __restrict__ el2, float* __restrict__ er2)
{
    __shared__ int   s_src[4][64];
    __shared__ float s_w[4][2][64];
    const int wv = threadIdx.x >> 6, lane = threadIdx.x & 63;
    const int n = blockIdx.x * 4 + wv;
    const int beg = row_start[n];
    const int deg = row_start[n+1] - beg;
    const float2 ern = *(const float2*)(er + 2*(size_t)n);
    const int h = lane >> 5;
    float ax = 0.f, ay = 0.f, dp0 = 0.f, dp1 = 0.f;

    for (int cb = 0; cb < deg; cb += 64) {
        const int cnt = min(64, deg - cb);
        float w0 = 0.f, w1 = 0.f; int s = 0;
        if (lane < cnt) {
            s = ssorted[beg + cb + lane];
            float2 e = *(const float2*)(el + 2*(size_t)s);
            w0 = __expf(lrelu(e.x + ern.x));     // no max subtraction: |logit| small
            w1 = __expf(lrelu(e.y + ern.y));
        }
        dp0 += w0; dp1 += w1;
        s_src[wv][lane] = s; s_w[wv][0][lane] = w0; s_w[wv][1][lane] = w1;
        asm volatile("s_waitcnt lgkmcnt(0)" ::: "memory");   // wave-synchronous LDS publish
        int t = 0;
        for (; t + 8 <= cnt; t += 8) {
            int4   sa = *(const int4*)&s_src[wv][t];
            int4   sb = *(const int4*)&s_src[wv][t+4];
            float4 wa = *(const float4*)&s_w[wv][h][t];
            float4 wb = *(const float4*)&s_w[wv][h][t+4];
            int   sv[8] = {sa.x,sa.y,sa.z,sa.w,sb.x,sb.y,sb.z,sb.w};
            float wj[8] = {wa.x,wa.y,wa.z,wa.w,wb.x,wb.y,wb.z,wb.w};
            uint U[8];
            #pragma unroll
            for (int j = 0; j < 8; j++) U[j] = ftb[((uint)sv[j] << 6) + lane];
            #pragma unroll
            for (int j = 0; j < 8; j++) { ax += wj[j]*blo(U[j]); ay += wj[j]*bhi(U[j]); }
        }
        for (; t + 4 <= cnt; t += 4) {
            int4   s4 = *(const int4*)&s_src[wv][t];
            float4 w4 = *(const float4*)&s_w[wv][h][t];
            uint u0 = ftb[((uint)s4.x << 6) + lane];
            uint u1 = ftb[((uint)s4.y << 6) + lane];
            uint u2 = ftb[((uint)s4.z << 6) + lane];
            uint u3 = ftb[((uint)s4.w << 6) + lane];
            ax += w4.x*blo(u0); ay += w4.x*bhi(u0);
            ax += w4.y*blo(u1); ay += w4.y*bhi(u1);
            ax += w4.z*blo(u2); ay += w4.z*bhi(u2);
            ax += w4.w*blo(u3); ay += w4.w*bhi(u3);
        }
        for (; t < cnt; t++) {
            int sv = s_src[wv][t];
            float w = s_w[wv][h][t];
            uint u = ftb[((uint)sv << 6) + lane];
            ax += w*blo(u); ay += w*bhi(u);
        }
    }
    #pragma unroll
    for (int off = 32; off; off >>= 1) { dp0 += __shfl_xor(dp0, off); dp1 += __shfl_xor(dp1, off); }
    const float den = (h == 0) ? dp0 : dp1;
    float r0 = (deg > 0) ? ax / den : 0.f;
    float r1 = (deg > 0) ? ay / den : 0.f;
    const int c0 = 2 * lane;
    const size_t ob = (size_t)n*128 + c0;
    const float2 bv = *(const float2*)(bias + c0);
    float v0 = r0 + bv.x, v1 = r1 + bv.y;
    if (MODE == 1) {
        ushort2 rv = *(const ushort2*)&Rb[ob];
        v0 += bf2f(rv.x);
        v1 += bf2f(rv.y);
    }
    v0 = elu_f(v0); v1 = elu_f(v1);
    *(ushort2*)&Hb[ob] = make_ushort2(f2bf(v0), f2bf(v1));

    if constexpr (MODE == 1) {
        float2 a0 = *(const float2*)(alp2 + c0);
        float2 a1 = *(const float2*)(alp2 + 128 + c0);
        float2 g0 = *(const float2*)(arp2 + c0);
        float2 g1 = *(const float2*)(arp2 + 128 + c0);
        float e0 = v0*a0.x + v1*a0.y;
        float e1 = v0*a1.x + v1*a1.y;
        float f0 = v0*g0.x + v1*g0.y;
        float f1 = v0*g1.x + v1*g1.y;
        #pragma unroll
        for (int off = 32; off; off >>= 1) {
            e0 += __shfl_xor(e0, off); e1 += __shfl_xor(e1, off);
            f0 += __shfl_xor(f0, off); f1 += __shfl_xor(f1, off);
        }
        if (lane == 0) {
            *(float2*)(el2 + 2*(size_t)n) = make_float2(e0, e1);
            *(float2*)(er2 + 2*(size_t)n) = make_float2(f0, f1);
        }
    }
}

// ================= layer-2 aggregation on h2 (linearity trick) =================
__global__ __launch_bounds__(256)
void gat_agg_out2(const uint* __restrict__ h2u, const float* __restrict__ el,
                  const float* __restrict__ er, const int* __restrict__ row_start,
                  const int* __restrict__ ssorted, u16* __restrict__ agg01)
{
    __shared__ int   s_src[4][64];
    __shared__ float s_w[4][2][64];
    const int wv = threadIdx.x >> 6, lane = threadIdx.x & 63;
    const int n = blockIdx.x * 4 + wv;
    const int beg = row_start[n];
    const int deg = row_start[n+1] - beg;
    const float2 ern = *(const float2*)(er + 2*(size_t)n);
    float ax0 = 0.f, ay0 = 0.f, ax1 = 0.f, ay1 = 0.f, dp0 = 0.f, dp1 = 0.f;

    for (int cb = 0; cb < deg; cb += 64) {
        const int cnt = min(64, deg - cb);
        float w0 = 0.f, w1 = 0.f; int s = 0;
        if (lane < cnt) {
            s = ssorted[beg + cb + lane];
            float2 e = *(const float2*)(el + 2*(size_t)s);
            w0 = __expf(lrelu(e.x + ern.x));
            w1 = __expf(lrelu(e.y + ern.y));
        }
        dp0 += w0; dp1 += w1;
        s_src[wv][lane] = s; s_w[wv][0][lane] = w0; s_w[wv][1][lane] = w1;
        asm volatile("s_waitcnt lgkmcnt(0)" ::: "memory");
        int t = 0;
        for (; t + 8 <= cnt; t += 8) {
            int4   sa = *(const int4*)&s_src[wv][t];
            int4   sb = *(const int4*)&s_src[wv][t+4];
            float4 p0a = *(const float4*)&s_w[wv][0][t];
            float4 p0b = *(const float4*)&s_w[wv][0][t+4];
            float4 p1a = *(const float4*)&s_w[wv][1][t];
            float4 p1b = *(const float4*)&s_w[wv][1][t+4];
            int   sv[8] = {sa.x,sa.y,sa.z,sa.w,sb.x,sb.y,sb.z,sb.w};
            float f0[8] = {p0a.x,p0a.y,p0a.z,p0a.w,p0b.x,p0b.y,p0b.z,p0b.w};
            float f1[8] = {p1a.x,p1a.y,p1a.z,p1a.w,p1b.x,p1b.y,p1b.z,p1b.w};
            uint U[8];
            #pragma unroll
            for (int j = 0; j < 8; j++) U[j] = h2u[((uint)sv[j] << 6) + lane];
            #pragma unroll
            for (int j = 0; j < 8; j++) {
                float lo = blo(U[j]), hi = bhi(U[j]);
                ax0 += f0[j]*lo; ay0 += f0[j]*hi;
                ax1 += f1[j]*lo; ay1 += f1[j]*hi;
            }
        }
        for (; t < cnt; t++) {
            int sv = s_src[wv][t];
            float f0 = s_w[wv][0][t], f1 = s_w[wv][1][t];
            uint u = h2u[((uint)sv << 6) + lane];
            float lo = blo(u), hi = bhi(u);
            ax0 += f0*lo; ay0 += f0*hi;
            ax1 += f1*lo; ay1 += f1*hi;
        }
    }
    #pragma unroll
    for (int off = 32; off; off >>= 1) { dp0 += __shfl_xor(dp0, off); dp1 += __shfl_xor(dp1, off); }
    const float i0 = (deg > 0) ? 1.f/dp0 : 0.f;
    const float i1 = (deg > 0) ? 1.f/dp1 : 0.f;
    const int c0 = 2 * lane;
    *(ushort2*)&agg01[(size_t)n*256 + c0]       = make_ushort2(f2bf(ax0*i0), f2bf(ay0*i0));
    *(ushort2*)&agg01[(size_t)n*256 + 128 + c0] = make_ushort2(f2bf(ax1*i1), f2bf(ay1*i1));
}

extern "C" void kernel_launch(void* const* d_in, const int* in_sizes, int n_in,
                              void* d_out, int out_size, void* d_ws, size_t ws_size,
                              hipStream_t stream)
{
    const float* x   = (const float*)d_in[0];
    const int*   esrc= (const int*)  d_in[1];
    const int*   edst= (const int*)  d_in[2];
    const float* W0  = (const float*)d_in[3];
    const float* al0 = (const float*)d_in[4];
    const float* ar0 = (const float*)d_in[5];
    const float* b0  = (const float*)d_in[6];
    const float* W1  = (const float*)d_in[7];
    const float* al1 = (const float*)d_in[8];
    const float* ar1 = (const float*)d_in[9];
    const float* b1  = (const float*)d_in[10];
    const float* W2  = (const float*)d_in[11];
    const float* al2 = (const float*)d_in[12];
    const float* ar2 = (const float*)d_in[13];
    const float* b2  = (const float*)d_in[14];
    const float* rW2 = (const float*)d_in[15];
    float* out = (float*)d_out;

    const int N = NNODES, E = NEDGES;
    const int NB = (N + 4095) / 4096;            // 13 scan tiles
    float* ws = (float*)d_ws;
    size_t o = 0;
    auto alloc_f = [&](size_t count) { float* p = ws + o; o += (count + 3) & ~(size_t)3; return p; };
    float* el    = alloc_f((size_t)N * 2);
    float* er    = alloc_f((size_t)N * 2);
    float* el2   = alloc_f((size_t)N * 2);
    float* er2   = alloc_f((size_t)N * 2);
    uint*  ftb   = (uint*)alloc_f((size_t)N * 64);         // bf16 ft [N][128]
    u16*   agg01 = (u16*)alloc_f((size_t)NPAD * 128);      // bf16 [NPAD][256]
    u16*   Xb    = (u16*)alloc_f((size_t)NPAD * 64);       // bf16 [NPAD][128] (x, then h2)
    u16*   H1b   = (u16*)alloc_f((size_t)NPAD * 64);
    u16*   B01   = (u16*)alloc_f(256 * 64);                // W0|W1 transposed bf16
    u16*   Bf    = (u16*)alloc_f(128 * 192);               // final-GEMM B' [128][384]
    float* alp2  = alloc_f(256);
    float* arp2  = alloc_f(256);
    float* cbv   = alloc_f(128);
    int* row_start = (int*)alloc_f(N + 4);
    int* cursor    = (int*)alloc_f(N + 64);                // counts/cursor + flags + prefixes
    int* flags     = cursor + N;
    int* prefixes  = cursor + N + 16;
    int* ssorted   = (int*)alloc_f(E);

    // ---- CSR + prep: memset, fused hist(first)+prep, scan (inits cursor), sliced scatter ----
    hipMemsetAsync(cursor, 0, (N + 64) * sizeof(int), stream);
    prep_hist<<<HISTB + PREPB, 256, 0, stream>>>(x, W0, W1, W2, rW2, al2, ar2, b2,
                                                 edst, cursor,
                                                 Xb, H1b, B01, Bf, alp2, arp2, cbv, N);
    scan_dl<<<NB, 1024, 0, stream>>>(cursor, row_start, flags, prefixes, N);
    scatter_sliced<<<NSLICE * 256, 256, 0, stream>>>(esrc, edst, cursor, ssorted, E);

    const int gx = NPAD / 128;                   // 391
    const int agg_grid = N / 4;                  // 12500

    // ---- layer 0 (GEMM + fused el/er) ----
    gemm_l01<<<gx, 512, 0, stream>>>(Xb, B01, (u16*)ftb, al0, ar0, el, er, N);
    gat_agg128<0><<<agg_grid, 256, 0, stream>>>(ftb, el, er, row_start, ssorted,
                                                nullptr, b0, H1b, nullptr, nullptr, nullptr, nullptr);

    // ---- layer 1 (identity residual; epilogue computes h2 + el2/er2) ----
    gemm_l01<<<gx, 512, 0, stream>>>(H1b, B01 + 128*128, (u16*)ftb, al1, ar1, el, er, N);
    gat_agg128<1><<<agg_grid, 256, 0, stream>>>(ftb, el, er, row_start, ssorted,
                                                H1b, b1, Xb, alp2, arp2, el2, er2);

    // ---- layer 2: aggregate h2 per head, then fused output GEMM ----
    gat_agg_out2<<<agg_grid, 256, 0, stream>>>((uint*)Xb, el2, er2, row_start, ssorted, agg01);
    gemm_final<<<((NPAD/64 + 7) / 8) * 16, 256, 0, stream>>>(agg01, Xb, Bf, cbv, out, N);
}